// Round 18
// baseline (638.115 us; speedup 1.0000x reference)
//
#include <hip/hip_runtime.h>
#include <stdint.h>

#define NNODES 100000
#define NEDGES 600000
#define NGRAPH 2048
#define DD 128
#define NLAYER 5
#define NPAD 100096   // 782*128 = 1564*64 = 391*256
#define SCAN_NB 391   // ceil(NNODES/256)
#define NSTAT 32      // stat copies to spread atomic contention

typedef __attribute__((ext_vector_type(8))) __bf16 bf16x8;
typedef __attribute__((ext_vector_type(4))) float f32x4;
typedef __attribute__((ext_vector_type(8))) ushort u16x8;

__device__ __forceinline__ ushort f2b(float f) {
    union { float f; uint32_t u; } v; v.f = f;
    uint32_t r = v.u + 0x7FFFu + ((v.u >> 16) & 1u);
    return (ushort)(r >> 16);
}

__device__ __forceinline__ float b2f(ushort u) {
    union { uint32_t u; float f; } v; v.u = ((uint32_t)u) << 16; return v.f;
}

__global__ void prep_w_kernel(const float* __restrict__ W1s, const float* __restrict__ W2s,
                              ushort* __restrict__ w1t, ushort* __restrict__ w2t) {
    int idx = blockIdx.x * 256 + threadIdx.x;
    const int per = 128 * 256;
    if (idx < NLAYER * per) {
        int i = idx / per, rem = idx % per;
        int n = rem >> 7, k = rem & 127;          // w1t[i][n(256)][k(128)] = W1s[i][k][n]
        w1t[idx] = f2b(W1s[(size_t)i * per + k * 256 + n]);
    } else if (idx < 2 * NLAYER * per) {
        int j = idx - NLAYER * per;
        int i = j / per, rem = j % per;
        int n = rem >> 8, k = rem & 255;          // w2t[i][n(128)][k(256)] = W2s[i][k][n]
        w2t[j] = f2b(W2s[(size_t)i * per + k * 128 + n]);
    }
}

// node embedding + vn init in one launch
__global__ void node_embed_kernel(const float* __restrict__ x, const float* __restrict__ W,
                                  const float* __restrict__ b, ushort* __restrict__ hb,
                                  const float* __restrict__ vne, float* __restrict__ vn) {
    int idx = blockIdx.x * 256 + threadIdx.x;
    if (idx < NNODES * 128) {
        int n = idx >> 7, d = idx & 127;
        float v = b[d];
#pragma unroll
        for (int k = 0; k < 9; ++k) v += x[n * 9 + k] * W[k * 128 + d];
        hb[(size_t)n * 128 + d] = f2b(v);
    } else if (idx < NNODES * 128 + NGRAPH * 128) {
        int r = idx - NNODES * 128;
        vn[r] = vne[r & 127];
    }
}

// ---------- CSR build (once per call; edges constant across layers) ----------

__global__ void deg_kernel(const int* __restrict__ dst, int* __restrict__ deg) {
    int e = blockIdx.x * 256 + threadIdx.x;
    if (e < NEDGES) atomicAdd(&deg[dst[e]], 1);
}

__global__ void scan_part_kernel(const int* __restrict__ deg, int* __restrict__ partials) {
    int i = blockIdx.x * 256 + threadIdx.x;
    int lane = threadIdx.x & 63, w = threadIdx.x >> 6;
    int v = (i < NNODES) ? deg[i] : 0;
#pragma unroll
    for (int o = 1; o < 64; o <<= 1) v += __shfl_xor(v, o);
    __shared__ int ws[4];
    if (lane == 0) ws[w] = v;
    __syncthreads();
    if (threadIdx.x == 0) partials[blockIdx.x] = ws[0] + ws[1] + ws[2] + ws[3];
}

__global__ __launch_bounds__(512)
void scan_top_kernel(int* __restrict__ partials) {
    __shared__ int s[512];
    int t = threadIdx.x;
    int v = (t < SCAN_NB) ? partials[t] : 0;
    s[t] = v;
    __syncthreads();
#pragma unroll
    for (int o = 1; o < 512; o <<= 1) {
        int n = (t >= o) ? s[t - o] : 0;
        __syncthreads();
        s[t] += n;
        __syncthreads();
    }
    if (t < SCAN_NB) partials[t] = s[t] - v;   // exclusive
}

__global__ void scan_blocks_kernel(const int* __restrict__ deg, const int* __restrict__ partials,
                                   int* __restrict__ rs, int* __restrict__ cursor) {
    int i = blockIdx.x * 256 + threadIdx.x;
    int lane = threadIdx.x & 63, w = threadIdx.x >> 6;
    int v = (i < NNODES) ? deg[i] : 0;
    int x = v;
#pragma unroll
    for (int o = 1; o < 64; o <<= 1) {
        int n = __shfl_up(x, o);
        if (lane >= o) x += n;
    }
    __shared__ int ws[4];
    if (lane == 63) ws[w] = x;
    __syncthreads();
    if (threadIdx.x == 0) {
        int a = 0;
#pragma unroll
        for (int k = 0; k < 4; ++k) { int t = ws[k]; ws[k] = a; a += t; }
    }
    __syncthreads();
    int excl = (x - v) + ws[w] + partials[blockIdx.x];
    if (i < NNODES) { rs[i] = excl; cursor[i] = excl; }
    if (i == 0) rs[NNODES] = NEDGES;
}

__global__ void csr_scatter_kernel(const int* __restrict__ src, const int* __restrict__ dst,
                                   int* __restrict__ cursor, int* __restrict__ csrc) {
    int e = blockIdx.x * 256 + threadIdx.x;
    if (e < NEDGES) {
        int p = atomicAdd(&cursor[dst[e]], 1);
        csrc[p] = src[e];
    }
}

__device__ __forceinline__ int lbound(const int* __restrict__ b, int key) {
    int lo = 0, hi = NNODES;
    while (lo < hi) { int m = (lo + hi) >> 1; if (b[m] < key) lo = m + 1; else hi = m; }
    return lo;
}

// per-graph row range + 1/cnt
__global__ void gstart_kernel(const int* __restrict__ batch, int* __restrict__ gstart,
                              float* __restrict__ inv) {
    int g = blockIdx.x * 256 + threadIdx.x;
    if (g <= NGRAPH)
        gstart[g] = (g == NGRAPH) ? NNODES : lbound(batch, g);
    if (g < NGRAPH) {
        int c = lbound(batch, g + 1) - lbound(batch, g);
        inv[g] = 1.f / (float)(c > 0 ? c : 1);
    }
}

// ---------- fused GIN agg + MLP (2 tiles/block, grid 782, swizzled lA stage) ----------
#define MLP_TILES 2
#define MLP_GRID 782   // NPAD/64/MLP_TILES
__global__ __launch_bounds__(256, 2)
void gin_mlp_kernel(const ushort* __restrict__ hb, const int* __restrict__ rs,
                    const int* __restrict__ csrc,
                    const ushort* __restrict__ W1, const float* __restrict__ b1,
                    const ushort* __restrict__ W2, const float* __restrict__ b2,
                    ushort* __restrict__ out_b, float* __restrict__ stats,
                    float* __restrict__ statsZero) {
    __shared__ __align__(16) ushort lA[8192];     // 16KB: [ks:4][q:4][row:64][8], 16B-XOR-swizzled
    __shared__ __align__(16) ushort mid[16384];   // 32KB: [g2:32][row:64][8]
    const int tid = threadIdx.x;
    const int lane = tid & 63, w = tid >> 6;
    const int q = lane >> 4, l16 = lane & 15;
    float* sbase = stats + (blockIdx.x & (NSTAT - 1)) * 256;

    if (blockIdx.x < NSTAT) statsZero[blockIdx.x * 256 + tid] = 0.f;

    // preload W1 fragments for this wave's n-quadrant (64 VGPRs)
    bf16x8 w1f[4][4];
#pragma unroll
    for (int ks = 0; ks < 4; ++ks)
#pragma unroll
        for (int ni = 0; ni < 4; ++ni)
            w1f[ks][ni] = *(const bf16x8*)(W1 + (size_t)(w * 64 + ni * 16 + l16) * 128 + ks * 32 + q * 8);

    const int row = tid >> 2, l4 = tid & 3;       // 4 threads per row, 32 elems each

    for (int tt = 0; tt < MLP_TILES; ++tt) {
        const int rb = blockIdx.x * (64 * MLP_TILES) + tt * 64;
        if (tt) __syncthreads();   // mid consumed before restaging lA

        // ---- stage: gather-aggregate into lA (swizzled) ----
        {
            int node = rb + row;
            float acc[32];
            if (node < NNODES) {
                const ushort* hrow = hb + (size_t)node * 128 + l4 * 32;
                u16x8 h0 = *(const u16x8*)(hrow);
                u16x8 h1 = *(const u16x8*)(hrow + 8);
                u16x8 h2 = *(const u16x8*)(hrow + 16);
                u16x8 h3 = *(const u16x8*)(hrow + 24);
#pragma unroll
                for (int k = 0; k < 8; ++k) {
                    acc[k] = b2f(h0[k]);      acc[8 + k]  = b2f(h1[k]);
                    acc[16 + k] = b2f(h2[k]); acc[24 + k] = b2f(h3[k]);
                }
                int s = rs[node], e = rs[node + 1];
                int k = s;
                for (; k + 1 < e; k += 2) {
                    const ushort* p0 = hb + (size_t)csrc[k] * 128 + l4 * 32;
                    const ushort* p1 = hb + (size_t)csrc[k + 1] * 128 + l4 * 32;
                    u16x8 a0 = *(const u16x8*)(p0);      u16x8 a1 = *(const u16x8*)(p0 + 8);
                    u16x8 a2 = *(const u16x8*)(p0 + 16); u16x8 a3 = *(const u16x8*)(p0 + 24);
                    u16x8 c0 = *(const u16x8*)(p1);      u16x8 c1 = *(const u16x8*)(p1 + 8);
                    u16x8 c2 = *(const u16x8*)(p1 + 16); u16x8 c3 = *(const u16x8*)(p1 + 24);
#pragma unroll
                    for (int m = 0; m < 8; ++m) {
                        acc[m]      += b2f(a0[m]) + b2f(c0[m]);
                        acc[8 + m]  += b2f(a1[m]) + b2f(c1[m]);
                        acc[16 + m] += b2f(a2[m]) + b2f(c2[m]);
                        acc[24 + m] += b2f(a3[m]) + b2f(c3[m]);
                    }
                }
                if (k < e) {
                    const ushort* p0 = hb + (size_t)csrc[k] * 128 + l4 * 32;
                    u16x8 a0 = *(const u16x8*)(p0);      u16x8 a1 = *(const u16x8*)(p0 + 8);
                    u16x8 a2 = *(const u16x8*)(p0 + 16); u16x8 a3 = *(const u16x8*)(p0 + 24);
#pragma unroll
                    for (int m = 0; m < 8; ++m) {
                        acc[m]      += b2f(a0[m]);
                        acc[8 + m]  += b2f(a1[m]);
                        acc[16 + m] += b2f(a2[m]);
                        acc[24 + m] += b2f(a3[m]);
                    }
                }
            } else {
#pragma unroll
                for (int m = 0; m < 32; ++m) acc[m] = 0.f;
            }
#pragma unroll
            for (int c = 0; c < 4; ++c) {
                int j = l4 * 4 + c;                // k-chunk index 0..15
                int ks = j >> 2, qq = j & 3;
                u16x8 o;
#pragma unroll
                for (int m = 0; m < 8; ++m) o[m] = f2b(acc[c * 8 + m]);
                int byteoff = (ks * 4096 + qq * 1024 + row * 16) ^ ((ks & 3) << 4);
                *(u16x8*)((char*)lA + byteoff) = o;
            }
        }
        __syncthreads();

        // ---- phase 1: C1[64][256] = A@W1 ----
        f32x4 acc1[4][4] = {};
#pragma unroll
        for (int ks = 0; ks < 4; ++ks) {
            bf16x8 af[4];
#pragma unroll
            for (int mi = 0; mi < 4; ++mi) {
                int byteoff = (ks * 4096 + q * 1024 + (mi * 16 + l16) * 16) ^ ((ks & 3) << 4);
                af[mi] = *(const bf16x8*)((const char*)lA + byteoff);
            }
#pragma unroll
            for (int mi = 0; mi < 4; ++mi)
#pragma unroll
                for (int ni = 0; ni < 4; ++ni)
                    acc1[mi][ni] = __builtin_amdgcn_mfma_f32_16x16x32_bf16(af[mi], w1f[ks][ni], acc1[mi][ni], 0, 0, 0);
        }

#pragma unroll
        for (int ni = 0; ni < 4; ++ni) {
            int col = w * 64 + ni * 16 + l16;
            float bs = b1[col];
            int g2 = col >> 3, jj = col & 7;
#pragma unroll
            for (int mi = 0; mi < 4; ++mi) {
                int rowb = mi * 16 + q * 4;
#pragma unroll
                for (int r = 0; r < 4; ++r) {
                    float v = acc1[mi][ni][r] + bs;
                    v = v > 0.f ? v : 0.f;
                    mid[g2 * 512 + (rowb + r) * 8 + jj] = f2b(v);
                }
            }
        }
        __syncthreads();

        // ---- phase 2: C2[64][128] = mid@W2 + b2 (W2 frags from L2) ----
        f32x4 acc2[4][2] = {};
#pragma unroll
        for (int ks = 0; ks < 8; ++ks) {
            bf16x8 af[4], bw[2];
#pragma unroll
            for (int mi = 0; mi < 4; ++mi)
                af[mi] = *(const bf16x8*)&mid[(ks * 4 + q) * 512 + (mi * 16 + l16) * 8];
#pragma unroll
            for (int ni = 0; ni < 2; ++ni)
                bw[ni] = *(const bf16x8*)(W2 + (size_t)(w * 32 + ni * 16 + l16) * 256 + ks * 32 + q * 8);
#pragma unroll
            for (int mi = 0; mi < 4; ++mi)
#pragma unroll
                for (int ni = 0; ni < 2; ++ni)
                    acc2[mi][ni] = __builtin_amdgcn_mfma_f32_16x16x32_bf16(af[mi], bw[ni], acc2[mi][ni], 0, 0, 0);
        }

#pragma unroll
        for (int ni = 0; ni < 2; ++ni) {
            int col = w * 32 + ni * 16 + l16;
            float bs = b2[col];
            float s = 0.f, sq = 0.f;
#pragma unroll
            for (int mi = 0; mi < 4; ++mi) {
                int rr = rb + mi * 16 + q * 4;
#pragma unroll
                for (int r = 0; r < 4; ++r) {
                    float v = acc2[mi][ni][r] + bs;
                    out_b[(size_t)(rr + r) * 128 + col] = f2b(v);
                    if (rr + r < NNODES) { s += v; sq += v * v; }
                }
            }
            s  += __shfl_xor(s, 16);  s  += __shfl_xor(s, 32);
            sq += __shfl_xor(sq, 16); sq += __shfl_xor(sq, 32);
            if (lane < 16) {
                atomicAdd(&sbase[col], s);
                atomicAdd(&sbase[128 + col], sq);
            }
        }
    }
}

// ---------- fused tail: pool relu(bn(m))+resid, vn MLP, apply; FINAL emits gf + f32 outN ----------
template<int FINAL>
__global__ __launch_bounds__(256)
void tail_kernel(const ushort* __restrict__ m, ushort* __restrict__ hb,
                 const float* __restrict__ stats,
                 const float* __restrict__ bng, const float* __restrict__ bnb,
                 const int* __restrict__ gstart, const float* __restrict__ inv,
                 const float* __restrict__ W1, const float* __restrict__ b1,
                 const float* __restrict__ W2, const float* __restrict__ b2,
                 float* __restrict__ vn, float* __restrict__ outN,
                 float* __restrict__ gf, int resid) {
    __shared__ float sC[128], sS[128];
    __shared__ float red[16][128];
    __shared__ float t[128], t1[128], vns[128];
    int g = blockIdx.x, tid = threadIdx.x;
    if (tid < 128) {
        int d = tid;
        float sum = 0.f, sq = 0.f;
#pragma unroll
        for (int c = 0; c < NSTAT; ++c) {
            sum += stats[c * 256 + d];
            sq  += stats[c * 256 + 128 + d];
        }
        float mu = sum * (1.f / NNODES);
        float var = sq * (1.f / NNODES) - mu * mu;
        var = var < 0.f ? 0.f : var;
        float sc = bng[d] * rsqrtf(var + 1e-5f);
        sC[d] = sc;
        sS[d] = bnb[d] - mu * sc;
    }
    __syncthreads();
    int j = tid & 15, rg = tid >> 4;           // 16 lanes x 16 row-groups
    float sc8[8], sh8[8], acc[8];
#pragma unroll
    for (int k = 0; k < 8; ++k) { sc8[k] = sC[j * 8 + k]; sh8[k] = sS[j * 8 + k]; acc[k] = 0.f; }
    int s = gstart[g], e = gstart[g + 1];

    // pass 1: pool w
    for (int r = s + rg; r < e; r += 16) {
        u16x8 mv = *(const u16x8*)(m + (size_t)r * 128 + j * 8);
        float v[8];
#pragma unroll
        for (int k = 0; k < 8; ++k) v[k] = fmaxf(b2f(mv[k]) * sc8[k] + sh8[k], 0.f);
        if (resid) {
            u16x8 hv = *(const u16x8*)(hb + (size_t)r * 128 + j * 8);
#pragma unroll
            for (int k = 0; k < 8; ++k) v[k] += b2f(hv[k]);
        }
#pragma unroll
        for (int k = 0; k < 8; ++k) acc[k] += v[k];
    }
#pragma unroll
    for (int k = 0; k < 8; ++k) red[rg][j * 8 + k] = acc[k];
    __syncthreads();
    if (tid < 128) {
        int d = tid;
        float tot = 0.f;
#pragma unroll
        for (int r2 = 0; r2 < 16; ++r2) tot += red[r2][d];
        t[d] = tot * inv[g];
    }
    __syncthreads();
    if (tid < 128) {
        int d = tid;
        float a = b1[d];
        for (int k = 0; k < 128; ++k) a += t[k] * W1[k * 128 + d];
        t1[d] = fmaxf(a, 0.f);
    }
    __syncthreads();
    if (tid < 128) {
        int d = tid;
        float o = b2[d];
        for (int k = 0; k < 128; ++k) o += t1[k] * W2[k * 128 + d];
        float vnew = vn[(size_t)g * 128 + d] + o;
        vn[(size_t)g * 128 + d] = vnew;
        vns[d] = vnew;
        if (FINAL) gf[(size_t)g * 128 + d] = (e > s) ? (t[d] + vnew) : 0.f;
    }
    __syncthreads();

    float vg[8];
#pragma unroll
    for (int k = 0; k < 8; ++k) vg[k] = vns[j * 8 + k];

    // pass 2: recompute w (L2-hot reads), emit h = w + vn_new
    for (int r = s + rg; r < e; r += 16) {
        u16x8 mv = *(const u16x8*)(m + (size_t)r * 128 + j * 8);
        float v[8];
#pragma unroll
        for (int k = 0; k < 8; ++k) v[k] = fmaxf(b2f(mv[k]) * sc8[k] + sh8[k], 0.f);
        if (resid) {
            u16x8 hv = *(const u16x8*)(hb + (size_t)r * 128 + j * 8);
#pragma unroll
            for (int k = 0; k < 8; ++k) v[k] += b2f(hv[k]);
        }
#pragma unroll
        for (int k = 0; k < 8; ++k) v[k] += vg[k];
        if (FINAL) {
            float4* op = (float4*)(outN + (size_t)r * 128 + j * 8);
            op[0] = make_float4(v[0], v[1], v[2], v[3]);
            op[1] = make_float4(v[4], v[5], v[6], v[7]);
        } else {
            u16x8 o;
#pragma unroll
            for (int k = 0; k < 8; ++k) o[k] = f2b(v[k]);
            *(u16x8*)(hb + (size_t)r * 128 + j * 8) = o;
        }
    }
}

// ---------- graph MLP: consumes precomputed gf (no pooling) ----------
__global__ __launch_bounds__(128)
void graph_mlp_kernel(const float* __restrict__ gf,
                      const float* __restrict__ W1, const float* __restrict__ b1,
                      const float* __restrict__ lng, const float* __restrict__ lnb,
                      const float* __restrict__ W2, const float* __restrict__ b2,
                      float* __restrict__ out) {
    __shared__ float t[128], t1[128], lred[2];
    int g = blockIdx.x, d = threadIdx.x;
    int lane = d & 63, w = d >> 6;
    t[d] = gf[(size_t)g * 128 + d];
    __syncthreads();
    float a = b1[d];
    for (int k = 0; k < 128; ++k) a += t[k] * W1[k * 128 + d];
    float ssum = a;
#pragma unroll
    for (int o = 1; o < 64; o <<= 1) ssum += __shfl_xor(ssum, o);
    if (lane == 0) lred[w] = ssum;
    __syncthreads();
    float mu = (lred[0] + lred[1]) * (1.f / 128.f);
    float dv = a - mu;
    float qq = dv * dv;
#pragma unroll
    for (int o = 1; o < 64; o <<= 1) qq += __shfl_xor(qq, o);
    __syncthreads();
    if (lane == 0) lred[w] = qq;
    __syncthreads();
    float var = (lred[0] + lred[1]) * (1.f / 128.f);
    float v = dv * rsqrtf(var + 1e-5f) * lng[d] + lnb[d];
    v = fmaxf(v, 0.f);
    t1[d] = v;
    __syncthreads();
    float o2 = b2[d];
    for (int k = 0; k < 128; ++k) o2 += t1[k] * W2[k * 128 + d];
    out[g * 128 + d] = o2;
}

extern "C" void kernel_launch(void* const* d_in, const int* in_sizes, int n_in,
                              void* d_out, int out_size, void* d_ws, size_t ws_size,
                              hipStream_t stream) {
    const float* x    = (const float*)d_in[0];
    const int*   edge = (const int*)d_in[1];
    const int*   src  = edge;
    const int*   dst  = edge + NEDGES;
    const int*   batch = (const int*)d_in[2];
    const float* nW   = (const float*)d_in[3];
    const float* nb   = (const float*)d_in[4];
    const float* W1s  = (const float*)d_in[5];
    const float* b1s  = (const float*)d_in[6];
    const float* W2s  = (const float*)d_in[7];
    const float* b2s  = (const float*)d_in[8];
    const float* bng  = (const float*)d_in[9];
    const float* bnb  = (const float*)d_in[10];
    const float* vne  = (const float*)d_in[11];
    const float* vW1  = (const float*)d_in[12];
    const float* vb1  = (const float*)d_in[13];
    const float* vW2  = (const float*)d_in[14];
    const float* vb2  = (const float*)d_in[15];
    const float* gW1  = (const float*)d_in[16];
    const float* gb1  = (const float*)d_in[17];
    const float* lng  = (const float*)d_in[18];
    const float* lnb  = (const float*)d_in[19];
    const float* gW2  = (const float*)d_in[20];
    const float* gb2  = (const float*)d_in[21];

    char* ws = (char*)d_ws;
    auto alloc = [&](size_t bytes) { char* p = ws; ws += (bytes + 255) & ~(size_t)255; return p; };
    float*  stats = (float*)alloc((size_t)2 * NSTAT * 256 * 4);  // double-buffered by layer parity
    ushort* hb    = (ushort*)alloc((size_t)NPAD * 128 * 2);      // h in bf16
    ushort* mbuf  = (ushort*)alloc((size_t)NPAD * 128 * 2);
    float*  vn    = (float*)alloc((size_t)NGRAPH * 128 * 4);
    float*  gf    = (float*)alloc((size_t)NGRAPH * 128 * 4);
    ushort* w1t   = (ushort*)alloc((size_t)NLAYER * 256 * 128 * 2);
    ushort* w2t   = (ushort*)alloc((size_t)NLAYER * 128 * 256 * 2);
    float*  inv   = (float*)alloc((size_t)NGRAPH * 4);
    int*    gstart= (int*)alloc((size_t)(NGRAPH + 1) * 4);
    int*    deg   = (int*)alloc((size_t)NNODES * 4);
    int*    rs    = (int*)alloc((size_t)(NNODES + 1) * 4);
    int*    cursor= (int*)alloc((size_t)NNODES * 4);
    int*    csrc  = (int*)alloc((size_t)NEDGES * 4);
    int*    partials = (int*)alloc((size_t)SCAN_NB * 4);

    float* outN = (float*)d_out;
    float* outG = outN + (size_t)NNODES * 128;

    hipMemsetAsync(stats, 0, (size_t)2 * NSTAT * 256 * 4, stream);
    hipMemsetAsync(deg, 0, (size_t)NNODES * 4, stream);

    // CSR build (edges constant across layers)
    deg_kernel<<<(NEDGES + 255) / 256, 256, 0, stream>>>(dst, deg);
    scan_part_kernel<<<SCAN_NB, 256, 0, stream>>>(deg, partials);
    scan_top_kernel<<<1, 512, 0, stream>>>(partials);
    scan_blocks_kernel<<<SCAN_NB, 256, 0, stream>>>(deg, partials, rs, cursor);
    csr_scatter_kernel<<<(NEDGES + 255) / 256, 256, 0, stream>>>(src, dst, cursor, csrc);
    gstart_kernel<<<(NGRAPH + 256) / 256, 256, 0, stream>>>(batch, gstart, inv);

    prep_w_kernel<<<(2 * NLAYER * 128 * 256 + 255) / 256, 256, 0, stream>>>(W1s, W2s, w1t, w2t);
    node_embed_kernel<<<((NNODES + NGRAPH) * 128 + 255) / 256, 256, 0, stream>>>(
        x, nW, nb, hb, vne, vn);

    for (int i = 0; i < NLAYER; ++i) {
        float* statsCur  = stats + (size_t)(i & 1) * NSTAT * 256;
        float* statsNext = stats + (size_t)((i + 1) & 1) * NSTAT * 256;
        gin_mlp_kernel<<<MLP_GRID, 256, 0, stream>>>(
            hb, rs, csrc,
            w1t + (size_t)i * 256 * 128, b1s + i * 256,
            w2t + (size_t)i * 128 * 256, b2s + i * 128,
            mbuf, statsCur, statsNext);
        if (i < NLAYER - 1)
            tail_kernel<0><<<NGRAPH, 256, 0, stream>>>(
                mbuf, hb, statsCur, bng + i * 128, bnb + i * 128, gstart, inv,
                vW1, vb1, vW2, vb2, vn, nullptr, nullptr, i > 0 ? 1 : 0);
        else
            tail_kernel<1><<<NGRAPH, 256, 0, stream>>>(
                mbuf, hb, statsCur, bng + i * 128, bnb + i * 128, gstart, inv,
                vW1, vb1, vW2, vb2, vn, outN, gf, 1);
    }
    graph_mlp_kernel<<<NGRAPH, 128, 0, stream>>>(gf, gW1, gb1, lng, lnb, gW2, gb2, outG);
}

// Round 19
// 573.306 us; speedup vs baseline: 1.1130x; 1.1130x over previous
//
#include <hip/hip_runtime.h>
#include <stdint.h>

#define NNODES 100000
#define NEDGES 600000
#define NGRAPH 2048
#define DD 128
#define NLAYER 5
#define NPAD 100096   // 782*128 = 1564*64 = 391*256
#define SCAN_NB 391   // ceil(NNODES/256)
#define NSTAT 32      // stat copies to spread atomic contention

typedef __attribute__((ext_vector_type(8))) __bf16 bf16x8;
typedef __attribute__((ext_vector_type(4))) float f32x4;
typedef __attribute__((ext_vector_type(8))) ushort u16x8;

__device__ __forceinline__ ushort f2b(float f) {
    union { float f; uint32_t u; } v; v.f = f;
    uint32_t r = v.u + 0x7FFFu + ((v.u >> 16) & 1u);
    return (ushort)(r >> 16);
}

__device__ __forceinline__ float b2f(ushort u) {
    union { uint32_t u; float f; } v; v.u = ((uint32_t)u) << 16; return v.f;
}

__global__ void prep_w_kernel(const float* __restrict__ W1s, const float* __restrict__ W2s,
                              ushort* __restrict__ w1t, ushort* __restrict__ w2t) {
    int idx = blockIdx.x * 256 + threadIdx.x;
    const int per = 128 * 256;
    if (idx < NLAYER * per) {
        int i = idx / per, rem = idx % per;
        int n = rem >> 7, k = rem & 127;          // w1t[i][n(256)][k(128)] = W1s[i][k][n]
        w1t[idx] = f2b(W1s[(size_t)i * per + k * 256 + n]);
    } else if (idx < 2 * NLAYER * per) {
        int j = idx - NLAYER * per;
        int i = j / per, rem = j % per;
        int n = rem >> 8, k = rem & 255;          // w2t[i][n(128)][k(256)] = W2s[i][k][n]
        w2t[j] = f2b(W2s[(size_t)i * per + k * 128 + n]);
    }
}

// node embedding + vn init in one launch
__global__ void node_embed_kernel(const float* __restrict__ x, const float* __restrict__ W,
                                  const float* __restrict__ b, ushort* __restrict__ hb,
                                  const float* __restrict__ vne, float* __restrict__ vn) {
    int idx = blockIdx.x * 256 + threadIdx.x;
    if (idx < NNODES * 128) {
        int n = idx >> 7, d = idx & 127;
        float v = b[d];
#pragma unroll
        for (int k = 0; k < 9; ++k) v += x[n * 9 + k] * W[k * 128 + d];
        hb[(size_t)n * 128 + d] = f2b(v);
    } else if (idx < NNODES * 128 + NGRAPH * 128) {
        int r = idx - NNODES * 128;
        vn[r] = vne[r & 127];
    }
}

// ---------- CSR build (once per call; edges constant across layers) ----------

__global__ void deg_kernel(const int* __restrict__ dst, int* __restrict__ deg) {
    int e = blockIdx.x * 256 + threadIdx.x;
    if (e < NEDGES) atomicAdd(&deg[dst[e]], 1);
}

__global__ void scan_part_kernel(const int* __restrict__ deg, int* __restrict__ partials) {
    int i = blockIdx.x * 256 + threadIdx.x;
    int lane = threadIdx.x & 63, w = threadIdx.x >> 6;
    int v = (i < NNODES) ? deg[i] : 0;
#pragma unroll
    for (int o = 1; o < 64; o <<= 1) v += __shfl_xor(v, o);
    __shared__ int ws[4];
    if (lane == 0) ws[w] = v;
    __syncthreads();
    if (threadIdx.x == 0) partials[blockIdx.x] = ws[0] + ws[1] + ws[2] + ws[3];
}

__global__ __launch_bounds__(512)
void scan_top_kernel(int* __restrict__ partials) {
    __shared__ int s[512];
    int t = threadIdx.x;
    int v = (t < SCAN_NB) ? partials[t] : 0;
    s[t] = v;
    __syncthreads();
#pragma unroll
    for (int o = 1; o < 512; o <<= 1) {
        int n = (t >= o) ? s[t - o] : 0;
        __syncthreads();
        s[t] += n;
        __syncthreads();
    }
    if (t < SCAN_NB) partials[t] = s[t] - v;   // exclusive
}

__global__ void scan_blocks_kernel(const int* __restrict__ deg, const int* __restrict__ partials,
                                   int* __restrict__ rs, int* __restrict__ cursor) {
    int i = blockIdx.x * 256 + threadIdx.x;
    int lane = threadIdx.x & 63, w = threadIdx.x >> 6;
    int v = (i < NNODES) ? deg[i] : 0;
    int x = v;
#pragma unroll
    for (int o = 1; o < 64; o <<= 1) {
        int n = __shfl_up(x, o);
        if (lane >= o) x += n;
    }
    __shared__ int ws[4];
    if (lane == 63) ws[w] = x;
    __syncthreads();
    if (threadIdx.x == 0) {
        int a = 0;
#pragma unroll
        for (int k = 0; k < 4; ++k) { int t = ws[k]; ws[k] = a; a += t; }
    }
    __syncthreads();
    int excl = (x - v) + ws[w] + partials[blockIdx.x];
    if (i < NNODES) { rs[i] = excl; cursor[i] = excl; }
    if (i == 0) rs[NNODES] = NEDGES;
}

__global__ void csr_scatter_kernel(const int* __restrict__ src, const int* __restrict__ dst,
                                   int* __restrict__ cursor, int* __restrict__ csrc) {
    int e = blockIdx.x * 256 + threadIdx.x;
    if (e < NEDGES) {
        int p = atomicAdd(&cursor[dst[e]], 1);
        csrc[p] = src[e];
    }
}

__device__ __forceinline__ int lbound(const int* __restrict__ b, int key) {
    int lo = 0, hi = NNODES;
    while (lo < hi) { int m = (lo + hi) >> 1; if (b[m] < key) lo = m + 1; else hi = m; }
    return lo;
}

// per-graph row range + 1/cnt
__global__ void gstart_kernel(const int* __restrict__ batch, int* __restrict__ gstart,
                              float* __restrict__ inv) {
    int g = blockIdx.x * 256 + threadIdx.x;
    if (g <= NGRAPH)
        gstart[g] = (g == NGRAPH) ? NNODES : lbound(batch, g);
    if (g < NGRAPH) {
        int c = lbound(batch, g + 1) - lbound(batch, g);
        inv[g] = 1.f / (float)(c > 0 ? c : 1);
    }
}

// ---------- fused GIN agg + MLP: CSR gather-aggregate staged straight into LDS, then 2 GEMMs ----------
// Per 64-row tile: 4 threads/row gather-aggregate h[node]+sum h[nbr] (f32) -> bf16 lA fragments,
// then C1 = A@W1 (W1 in regs), relu -> mid (LDS), C2 = mid@W2 (W2 from L2) -> mbuf + BN stats.
// Zeroes the OTHER stats parity (for the next layer) at start.
#define MLP_TILES 4
#define MLP_GRID 391   // NPAD/64/MLP_TILES
__global__ __launch_bounds__(256, 2)
void gin_mlp_kernel(const ushort* __restrict__ hb, const int* __restrict__ rs,
                    const int* __restrict__ csrc,
                    const ushort* __restrict__ W1, const float* __restrict__ b1,
                    const ushort* __restrict__ W2, const float* __restrict__ b2,
                    ushort* __restrict__ out_b, float* __restrict__ stats,
                    float* __restrict__ statsZero) {
    __shared__ __align__(16) ushort lA[8192];     // 16KB: [ks:4][q:4][row:64][8]
    __shared__ __align__(16) ushort mid[16384];   // 32KB: [g2:32][row:64][8]
    const int tid = threadIdx.x;
    const int lane = tid & 63, w = tid >> 6;
    const int q = lane >> 4, l16 = lane & 15;
    float* sbase = stats + (blockIdx.x & (NSTAT - 1)) * 256;

    if (blockIdx.x < NSTAT) statsZero[blockIdx.x * 256 + tid] = 0.f;

    // preload W1 fragments for this wave's n-quadrant (64 VGPRs)
    bf16x8 w1f[4][4];
#pragma unroll
    for (int ks = 0; ks < 4; ++ks)
#pragma unroll
        for (int ni = 0; ni < 4; ++ni)
            w1f[ks][ni] = *(const bf16x8*)(W1 + (size_t)(w * 64 + ni * 16 + l16) * 128 + ks * 32 + q * 8);

    const int row = tid >> 2, l4 = tid & 3;       // 4 threads per row, 32 elems each

    for (int tt = 0; tt < MLP_TILES; ++tt) {
        const int rb = blockIdx.x * (64 * MLP_TILES) + tt * 64;

        // ---- stage: gather-aggregate into lA ----
        {
            int node = rb + row;
            float acc[32];
            if (node < NNODES) {
                const ushort* hrow = hb + (size_t)node * 128 + l4 * 32;
                u16x8 h0 = *(const u16x8*)(hrow);
                u16x8 h1 = *(const u16x8*)(hrow + 8);
                u16x8 h2 = *(const u16x8*)(hrow + 16);
                u16x8 h3 = *(const u16x8*)(hrow + 24);
#pragma unroll
                for (int k = 0; k < 8; ++k) {
                    acc[k] = b2f(h0[k]);      acc[8 + k]  = b2f(h1[k]);
                    acc[16 + k] = b2f(h2[k]); acc[24 + k] = b2f(h3[k]);
                }
                int s = rs[node], e = rs[node + 1];
                int k = s;
                for (; k + 1 < e; k += 2) {
                    const ushort* p0 = hb + (size_t)csrc[k] * 128 + l4 * 32;
                    const ushort* p1 = hb + (size_t)csrc[k + 1] * 128 + l4 * 32;
                    u16x8 a0 = *(const u16x8*)(p0);      u16x8 a1 = *(const u16x8*)(p0 + 8);
                    u16x8 a2 = *(const u16x8*)(p0 + 16); u16x8 a3 = *(const u16x8*)(p0 + 24);
                    u16x8 c0 = *(const u16x8*)(p1);      u16x8 c1 = *(const u16x8*)(p1 + 8);
                    u16x8 c2 = *(const u16x8*)(p1 + 16); u16x8 c3 = *(const u16x8*)(p1 + 24);
#pragma unroll
                    for (int m = 0; m < 8; ++m) {
                        acc[m]      += b2f(a0[m]) + b2f(c0[m]);
                        acc[8 + m]  += b2f(a1[m]) + b2f(c1[m]);
                        acc[16 + m] += b2f(a2[m]) + b2f(c2[m]);
                        acc[24 + m] += b2f(a3[m]) + b2f(c3[m]);
                    }
                }
                if (k < e) {
                    const ushort* p0 = hb + (size_t)csrc[k] * 128 + l4 * 32;
                    u16x8 a0 = *(const u16x8*)(p0);      u16x8 a1 = *(const u16x8*)(p0 + 8);
                    u16x8 a2 = *(const u16x8*)(p0 + 16); u16x8 a3 = *(const u16x8*)(p0 + 24);
#pragma unroll
                    for (int m = 0; m < 8; ++m) {
                        acc[m]      += b2f(a0[m]);
                        acc[8 + m]  += b2f(a1[m]);
                        acc[16 + m] += b2f(a2[m]);
                        acc[24 + m] += b2f(a3[m]);
                    }
                }
            } else {
#pragma unroll
                for (int m = 0; m < 32; ++m) acc[m] = 0.f;
            }
#pragma unroll
            for (int c = 0; c < 4; ++c) {
                int j = l4 * 4 + c;                // k-chunk index 0..15
                int ks = j >> 2, qq = j & 3;
                u16x8 o;
#pragma unroll
                for (int m = 0; m < 8; ++m) o[m] = f2b(acc[c * 8 + m]);
                *(u16x8*)&lA[ks * 2048 + qq * 512 + row * 8] = o;
            }
        }
        __syncthreads();

        // ---- phase 1: C1[64][256] = A@W1 ----
        f32x4 acc1[4][4] = {};
#pragma unroll
        for (int ks = 0; ks < 4; ++ks) {
            bf16x8 af[4];
#pragma unroll
            for (int mi = 0; mi < 4; ++mi)
                af[mi] = *(const bf16x8*)&lA[ks * 2048 + q * 512 + (mi * 16 + l16) * 8];
#pragma unroll
            for (int mi = 0; mi < 4; ++mi)
#pragma unroll
                for (int ni = 0; ni < 4; ++ni)
                    acc1[mi][ni] = __builtin_amdgcn_mfma_f32_16x16x32_bf16(af[mi], w1f[ks][ni], acc1[mi][ni], 0, 0, 0);
        }

#pragma unroll
        for (int ni = 0; ni < 4; ++ni) {
            int col = w * 64 + ni * 16 + l16;
            float bs = b1[col];
            int g2 = col >> 3, jj = col & 7;
#pragma unroll
            for (int mi = 0; mi < 4; ++mi) {
                int rowb = mi * 16 + q * 4;
#pragma unroll
                for (int r = 0; r < 4; ++r) {
                    float v = acc1[mi][ni][r] + bs;
                    v = v > 0.f ? v : 0.f;
                    mid[g2 * 512 + (rowb + r) * 8 + jj] = f2b(v);
                }
            }
        }
        __syncthreads();

        // ---- phase 2: C2[64][128] = mid@W2 + b2 (W2 frags from L2) ----
        f32x4 acc2[4][2] = {};
#pragma unroll
        for (int ks = 0; ks < 8; ++ks) {
            bf16x8 af[4], bw[2];
#pragma unroll
            for (int mi = 0; mi < 4; ++mi)
                af[mi] = *(const bf16x8*)&mid[(ks * 4 + q) * 512 + (mi * 16 + l16) * 8];
#pragma unroll
            for (int ni = 0; ni < 2; ++ni)
                bw[ni] = *(const bf16x8*)(W2 + (size_t)(w * 32 + ni * 16 + l16) * 256 + ks * 32 + q * 8);
#pragma unroll
            for (int mi = 0; mi < 4; ++mi)
#pragma unroll
                for (int ni = 0; ni < 2; ++ni)
                    acc2[mi][ni] = __builtin_amdgcn_mfma_f32_16x16x32_bf16(af[mi], bw[ni], acc2[mi][ni], 0, 0, 0);
        }

#pragma unroll
        for (int ni = 0; ni < 2; ++ni) {
            int col = w * 32 + ni * 16 + l16;
            float bs = b2[col];
            float s = 0.f, sq = 0.f;
#pragma unroll
            for (int mi = 0; mi < 4; ++mi) {
                int rr = rb + mi * 16 + q * 4;
#pragma unroll
                for (int r = 0; r < 4; ++r) {
                    float v = acc2[mi][ni][r] + bs;
                    out_b[(size_t)(rr + r) * 128 + col] = f2b(v);
                    if (rr + r < NNODES) { s += v; sq += v * v; }
                }
            }
            s  += __shfl_xor(s, 16);  s  += __shfl_xor(s, 32);
            sq += __shfl_xor(sq, 16); sq += __shfl_xor(sq, 32);
            if (lane < 16) {
                atomicAdd(&sbase[col], s);
                atomicAdd(&sbase[128 + col], sq);
            }
        }
        __syncthreads();   // mid consumed; lA free for next stage
    }
}

// ---------- fused tail: pool relu(bn(m))+resid, vn MLP, apply; FINAL emits gf + f32 outN ----------
template<int FINAL>
__global__ __launch_bounds__(256)
void tail_kernel(const ushort* __restrict__ m, ushort* __restrict__ hb,
                 const float* __restrict__ stats,
                 const float* __restrict__ bng, const float* __restrict__ bnb,
                 const int* __restrict__ gstart, const float* __restrict__ inv,
                 const float* __restrict__ W1, const float* __restrict__ b1,
                 const float* __restrict__ W2, const float* __restrict__ b2,
                 float* __restrict__ vn, float* __restrict__ outN,
                 float* __restrict__ gf, int resid) {
    __shared__ float sC[128], sS[128];
    __shared__ float red[16][128];
    __shared__ float t[128], t1[128], vns[128];
    int g = blockIdx.x, tid = threadIdx.x;
    if (tid < 128) {
        int d = tid;
        float sum = 0.f, sq = 0.f;
#pragma unroll
        for (int c = 0; c < NSTAT; ++c) {
            sum += stats[c * 256 + d];
            sq  += stats[c * 256 + 128 + d];
        }
        float mu = sum * (1.f / NNODES);
        float var = sq * (1.f / NNODES) - mu * mu;
        var = var < 0.f ? 0.f : var;
        float sc = bng[d] * rsqrtf(var + 1e-5f);
        sC[d] = sc;
        sS[d] = bnb[d] - mu * sc;
    }
    __syncthreads();
    int j = tid & 15, rg = tid >> 4;           // 16 lanes x 16 row-groups
    float sc8[8], sh8[8], acc[8];
#pragma unroll
    for (int k = 0; k < 8; ++k) { sc8[k] = sC[j * 8 + k]; sh8[k] = sS[j * 8 + k]; acc[k] = 0.f; }
    int s = gstart[g], e = gstart[g + 1];

    // pass 1: pool w
    for (int r = s + rg; r < e; r += 16) {
        u16x8 mv = *(const u16x8*)(m + (size_t)r * 128 + j * 8);
        float v[8];
#pragma unroll
        for (int k = 0; k < 8; ++k) v[k] = fmaxf(b2f(mv[k]) * sc8[k] + sh8[k], 0.f);
        if (resid) {
            u16x8 hv = *(const u16x8*)(hb + (size_t)r * 128 + j * 8);
#pragma unroll
            for (int k = 0; k < 8; ++k) v[k] += b2f(hv[k]);
        }
#pragma unroll
        for (int k = 0; k < 8; ++k) acc[k] += v[k];
    }
#pragma unroll
    for (int k = 0; k < 8; ++k) red[rg][j * 8 + k] = acc[k];
    __syncthreads();
    if (tid < 128) {
        int d = tid;
        float tot = 0.f;
#pragma unroll
        for (int r2 = 0; r2 < 16; ++r2) tot += red[r2][d];
        t[d] = tot * inv[g];
    }
    __syncthreads();
    if (tid < 128) {
        int d = tid;
        float a = b1[d];
        for (int k = 0; k < 128; ++k) a += t[k] * W1[k * 128 + d];
        t1[d] = fmaxf(a, 0.f);
    }
    __syncthreads();
    if (tid < 128) {
        int d = tid;
        float o = b2[d];
        for (int k = 0; k < 128; ++k) o += t1[k] * W2[k * 128 + d];
        float vnew = vn[(size_t)g * 128 + d] + o;
        vn[(size_t)g * 128 + d] = vnew;
        vns[d] = vnew;
        if (FINAL) gf[(size_t)g * 128 + d] = (e > s) ? (t[d] + vnew) : 0.f;
    }
    __syncthreads();

    float vg[8];
#pragma unroll
    for (int k = 0; k < 8; ++k) vg[k] = vns[j * 8 + k];

    // pass 2: recompute w (L2-hot reads), emit h = w + vn_new
    for (int r = s + rg; r < e; r += 16) {
        u16x8 mv = *(const u16x8*)(m + (size_t)r * 128 + j * 8);
        float v[8];
#pragma unroll
        for (int k = 0; k < 8; ++k) v[k] = fmaxf(b2f(mv[k]) * sc8[k] + sh8[k], 0.f);
        if (resid) {
            u16x8 hv = *(const u16x8*)(hb + (size_t)r * 128 + j * 8);
#pragma unroll
            for (int k = 0; k < 8; ++k) v[k] += b2f(hv[k]);
        }
#pragma unroll
        for (int k = 0; k < 8; ++k) v[k] += vg[k];
        if (FINAL) {
            float4* op = (float4*)(outN + (size_t)r * 128 + j * 8);
            op[0] = make_float4(v[0], v[1], v[2], v[3]);
            op[1] = make_float4(v[4], v[5], v[6], v[7]);
        } else {
            u16x8 o;
#pragma unroll
            for (int k = 0; k < 8; ++k) o[k] = f2b(v[k]);
            *(u16x8*)(hb + (size_t)r * 128 + j * 8) = o;
        }
    }
}

// ---------- graph MLP: consumes precomputed gf (no pooling) ----------
__global__ __launch_bounds__(128)
void graph_mlp_kernel(const float* __restrict__ gf,
                      const float* __restrict__ W1, const float* __restrict__ b1,
                      const float* __restrict__ lng, const float* __restrict__ lnb,
                      const float* __restrict__ W2, const float* __restrict__ b2,
                      float* __restrict__ out) {
    __shared__ float t[128], t1[128], lred[2];
    int g = blockIdx.x, d = threadIdx.x;
    int lane = d & 63, w = d >> 6;
    t[d] = gf[(size_t)g * 128 + d];
    __syncthreads();
    float a = b1[d];
    for (int k = 0; k < 128; ++k) a += t[k] * W1[k * 128 + d];
    float ssum = a;
#pragma unroll
    for (int o = 1; o < 64; o <<= 1) ssum += __shfl_xor(ssum, o);
    if (lane == 0) lred[w] = ssum;
    __syncthreads();
    float mu = (lred[0] + lred[1]) * (1.f / 128.f);
    float dv = a - mu;
    float qq = dv * dv;
#pragma unroll
    for (int o = 1; o < 64; o <<= 1) qq += __shfl_xor(qq, o);
    __syncthreads();
    if (lane == 0) lred[w] = qq;
    __syncthreads();
    float var = (lred[0] + lred[1]) * (1.f / 128.f);
    float v = dv * rsqrtf(var + 1e-5f) * lng[d] + lnb[d];
    v = fmaxf(v, 0.f);
    t1[d] = v;
    __syncthreads();
    float o2 = b2[d];
    for (int k = 0; k < 128; ++k) o2 += t1[k] * W2[k * 128 + d];
    out[g * 128 + d] = o2;
}

extern "C" void kernel_launch(void* const* d_in, const int* in_sizes, int n_in,
                              void* d_out, int out_size, void* d_ws, size_t ws_size,
                              hipStream_t stream) {
    const float* x    = (const float*)d_in[0];
    const int*   edge = (const int*)d_in[1];
    const int*   src  = edge;
    const int*   dst  = edge + NEDGES;
    const int*   batch = (const int*)d_in[2];
    const float* nW   = (const float*)d_in[3];
    const float* nb   = (const float*)d_in[4];
    const float* W1s  = (const float*)d_in[5];
    const float* b1s  = (const float*)d_in[6];
    const float* W2s  = (const float*)d_in[7];
    const float* b2s  = (const float*)d_in[8];
    const float* bng  = (const float*)d_in[9];
    const float* bnb  = (const float*)d_in[10];
    const float* vne  = (const float*)d_in[11];
    const float* vW1  = (const float*)d_in[12];
    const float* vb1  = (const float*)d_in[13];
    const float* vW2  = (const float*)d_in[14];
    const float* vb2  = (const float*)d_in[15];
    const float* gW1  = (const float*)d_in[16];
    const float* gb1  = (const float*)d_in[17];
    const float* lng  = (const float*)d_in[18];
    const float* lnb  = (const float*)d_in[19];
    const float* gW2  = (const float*)d_in[20];
    const float* gb2  = (const float*)d_in[21];

    char* ws = (char*)d_ws;
    auto alloc = [&](size_t bytes) { char* p = ws; ws += (bytes + 255) & ~(size_t)255; return p; };
    float*  stats = (float*)alloc((size_t)2 * NSTAT * 256 * 4);  // double-buffered by layer parity
    ushort* hb    = (ushort*)alloc((size_t)NPAD * 128 * 2);      // h in bf16
    ushort* mbuf  = (ushort*)alloc((size_t)NPAD * 128 * 2);
    float*  vn    = (float*)alloc((size_t)NGRAPH * 128 * 4);
    float*  gf    = (float*)alloc((size_t)NGRAPH * 128 * 4);
    ushort* w1t   = (ushort*)alloc((size_t)NLAYER * 256 * 128 * 2);
    ushort* w2t   = (ushort*)alloc((size_t)NLAYER * 128 * 256 * 2);
    float*  inv   = (float*)alloc((size_t)NGRAPH * 4);
    int*    gstart= (int*)alloc((size_t)(NGRAPH + 1) * 4);
    int*    deg   = (int*)alloc((size_t)NNODES * 4);
    int*    rs    = (int*)alloc((size_t)(NNODES + 1) * 4);
    int*    cursor= (int*)alloc((size_t)NNODES * 4);
    int*    csrc  = (int*)alloc((size_t)NEDGES * 4);
    int*    partials = (int*)alloc((size_t)SCAN_NB * 4);

    float* outN = (float*)d_out;
    float* outG = outN + (size_t)NNODES * 128;

    hipMemsetAsync(stats, 0, (size_t)2 * NSTAT * 256 * 4, stream);
    hipMemsetAsync(deg, 0, (size_t)NNODES * 4, stream);

    // CSR build (edges constant across layers)
    deg_kernel<<<(NEDGES + 255) / 256, 256, 0, stream>>>(dst, deg);
    scan_part_kernel<<<SCAN_NB, 256, 0, stream>>>(deg, partials);
    scan_top_kernel<<<1, 512, 0, stream>>>(partials);
    scan_blocks_kernel<<<SCAN_NB, 256, 0, stream>>>(deg, partials, rs, cursor);
    csr_scatter_kernel<<<(NEDGES + 255) / 256, 256, 0, stream>>>(src, dst, cursor, csrc);
    gstart_kernel<<<(NGRAPH + 256) / 256, 256, 0, stream>>>(batch, gstart, inv);

    prep_w_kernel<<<(2 * NLAYER * 128 * 256 + 255) / 256, 256, 0, stream>>>(W1s, W2s, w1t, w2t);
    node_embed_kernel<<<((NNODES + NGRAPH) * 128 + 255) / 256, 256, 0, stream>>>(
        x, nW, nb, hb, vne, vn);

    for (int i = 0; i < NLAYER; ++i) {
        float* statsCur  = stats + (size_t)(i & 1) * NSTAT * 256;
        float* statsNext = stats + (size_t)((i + 1) & 1) * NSTAT * 256;
        gin_mlp_kernel<<<MLP_GRID, 256, 0, stream>>>(
            hb, rs, csrc,
            w1t + (size_t)i * 256 * 128, b1s + i * 256,
            w2t + (size_t)i * 128 * 256, b2s + i * 128,
            mbuf, statsCur, statsNext);
        if (i < NLAYER - 1)
            tail_kernel<0><<<NGRAPH, 256, 0, stream>>>(
                mbuf, hb, statsCur, bng + i * 128, bnb + i * 128, gstart, inv,
                vW1, vb1, vW2, vb2, vn, nullptr, nullptr, i > 0 ? 1 : 0);
        else
            tail_kernel<1><<<NGRAPH, 256, 0, stream>>>(
                mbuf, hb, statsCur, bng + i * 128, bnb + i * 128, gstart, inv,
                vW1, vb1, vW2, vb2, vn, outN, gf, 1);
    }
    graph_mlp_kernel<<<NGRAPH, 128, 0, stream>>>(gf, gW1, gb1, lng, lnb, gW2, gb2, outG);
}